// Round 1
// baseline (1291.500 us; speedup 1.0000x reference)
//
#include <hip/hip_runtime.h>

#define B_ 16
#define C_ 128
#define N_ 16384
#define TN 64
#define NWAVE 4

// Pre-kernel: wqsum[i] = sum_o Wq[o][i]  (column sums of Wq)
__global__ __launch_bounds__(128) void wq_colsum_kernel(const float* __restrict__ Wq,
                                                        float* __restrict__ wqsum) {
  int i = threadIdx.x;
  float s = 0.f;
#pragma unroll 8
  for (int o = 0; o < C_; ++o) s += Wq[o * C_ + i];
  wqsum[i] = s;
}

// Main kernel: one block per (batch, 64-column tile).
// lanes <-> columns (n), waves <-> 32-row j-slices (W reads wave-uniform -> s_load).
__global__ __launch_bounds__(256, 2) void csa_kernel(
    const float* __restrict__ feature, const float* __restrict__ position,
    const float* __restrict__ Wk, const float* __restrict__ Wv,
    const float* __restrict__ wqsum, float* __restrict__ out) {
  __shared__ float pos_s[C_ * TN];   // [i][n], 32 KB
  __shared__ float feat_s[C_ * TN];  // [i][n], 32 KB
  __shared__ float red_sum[NWAVE][TN];
  __shared__ float red_max[NWAVE][TN];
  __shared__ float red_min[NWAVE][TN];
  __shared__ float red_es[NWAVE][TN];

  const int tid = threadIdx.x;
  const int lane = tid & 63;
  const int wv = tid >> 6;
  const int ntiles = N_ / TN;
  const int b = blockIdx.x / ntiles;
  const int n0 = (blockIdx.x % ntiles) * TN;

  const float* pos_g = position + (size_t)b * C_ * N_ + n0;
  const float* feat_g = feature + (size_t)b * C_ * N_ + n0;

  // Stage both tiles: coalesced float4 loads (4x 256B segments / wave instr).
#pragma unroll
  for (int k = 0; k < 8; ++k) {
    int flat = k * 1024 + tid * 4;  // word index in [128][64] tile
    int i = flat >> 6;
    int n = flat & 63;
    *(float4*)(pos_s + flat) = *(const float4*)(pos_g + (size_t)i * N_ + n);
    *(float4*)(feat_s + flat) = *(const float4*)(feat_g + (size_t)i * N_ + n);
  }
  __syncthreads();

  const int j0 = __builtin_amdgcn_readfirstlane(wv * 32);
  const float* __restrict__ wkb = Wk + j0 * C_;

  // Phase 1: k[j0..j0+31][col] for this lane's column.
  float acc[32];
#pragma unroll
  for (int jj = 0; jj < 32; ++jj) acc[jj] = 0.f;

#pragma unroll 2
  for (int c = 0; c < 16; ++c) {  // i-chunks of 8
    float x[8];
#pragma unroll
    for (int t = 0; t < 8; ++t) x[t] = pos_s[(c * 8 + t) * TN + lane];
#pragma unroll
    for (int jj = 0; jj < 32; ++jj) {
      const float* wr = wkb + jj * C_ + c * 8;  // wave-uniform -> s_load_dwordx8
#pragma unroll
      for (int t = 0; t < 8; ++t) acc[jj] = fmaf(wr[t], x[t], acc[jj]);
    }
  }

  // sq[col] = wqsum . pos[:,col]  (computed redundantly per wave; cheap)
  float sq = 0.f;
#pragma unroll 8
  for (int i = 0; i < C_; ++i) sq = fmaf(wqsum[i], pos_s[i * TN + lane], sq);

  // Per-wave partials of sum/max/min over j.
  float psum = 0.f, pmx = -__builtin_inff(), pmn = __builtin_inff();
#pragma unroll
  for (int jj = 0; jj < 32; ++jj) {
    psum += acc[jj];
    pmx = fmaxf(pmx, acc[jj]);
    pmn = fminf(pmn, acc[jj]);
  }
  red_sum[wv][lane] = psum;
  red_max[wv][lane] = pmx;
  red_min[wv][lane] = pmn;
  __syncthreads();

  float ksum = red_sum[0][lane] + red_sum[1][lane] + red_sum[2][lane] + red_sum[3][lane];
  float kmx = fmaxf(fmaxf(red_max[0][lane], red_max[1][lane]),
                    fmaxf(red_max[2][lane], red_max[3][lane]));
  float kmn = fminf(fminf(red_min[0][lane], red_min[1][lane]),
                    fminf(red_min[2][lane], red_min[3][lane]));

  // logits = g * k[j];   g = sq / (1e-9 + sq*ksum)
  float g = sq / (1e-9f + sq * ksum);
  float m = (g >= 0.f) ? g * kmx : g * kmn;  // max_j logits

  float es = 0.f;
#pragma unroll
  for (int jj = 0; jj < 32; ++jj) {
    acc[jj] = __expf(g * acc[jj] - m);  // p[j], unnormalized
    es += acc[jj];
  }
  red_es[wv][lane] = es;
  __syncthreads();

  float ssum = red_es[0][lane] + red_es[1][lane] + red_es[2][lane] + red_es[3][lane];
  float inv = 1.f / ssum;

  // Phase 2: v[j0..j0+31][col] from feat tile.
  const float* __restrict__ wvb = Wv + j0 * C_;
  float acc2[32];
#pragma unroll
  for (int jj = 0; jj < 32; ++jj) acc2[jj] = 0.f;

#pragma unroll 2
  for (int c = 0; c < 16; ++c) {
    float x[8];
#pragma unroll
    for (int t = 0; t < 8; ++t) x[t] = feat_s[(c * 8 + t) * TN + lane];
#pragma unroll
    for (int jj = 0; jj < 32; ++jj) {
      const float* wr = wvb + jj * C_ + c * 8;
#pragma unroll
      for (int t = 0; t < 8; ++t) acc2[jj] = fmaf(wr[t], x[t], acc2[jj]);
    }
  }

  // Epilogue: out = att*v + feat, coalesced 256B stores per j-row.
  float* outb = out + (size_t)b * C_ * N_ + n0;
#pragma unroll
  for (int jj = 0; jj < 32; ++jj) {
    int j = j0 + jj;
    outb[(size_t)j * N_ + lane] = fmaf(acc[jj] * inv, acc2[jj], feat_s[j * TN + lane]);
  }
}

extern "C" void kernel_launch(void* const* d_in, const int* in_sizes, int n_in,
                              void* d_out, int out_size, void* d_ws, size_t ws_size,
                              hipStream_t stream) {
  const float* feature = (const float*)d_in[0];
  const float* position = (const float*)d_in[1];
  const float* Wq = (const float*)d_in[2];
  const float* Wk = (const float*)d_in[3];
  const float* Wv = (const float*)d_in[4];
  float* out = (float*)d_out;
  float* wqsum = (float*)d_ws;  // 128 floats of scratch

  wq_colsum_kernel<<<1, 128, 0, stream>>>(Wq, wqsum);
  csa_kernel<<<B_ * (N_ / TN), 256, 0, stream>>>(feature, position, Wk, Wv, wqsum, out);
}

// Round 2
// 521.486 us; speedup vs baseline: 2.4766x; 2.4766x over previous
//
#include <hip/hip_runtime.h>

#define B_ 16
#define C_ 128
#define N_ 16384
#define TN 64

typedef __attribute__((ext_vector_type(8))) short short8;
typedef __attribute__((ext_vector_type(4))) float f32x4;

__device__ inline unsigned short bf16_rn(float x) {
  unsigned u = __float_as_uint(x);
  unsigned r = u + 0x7FFFu + ((u >> 16) & 1u);
  return (unsigned short)(r >> 16);
}

// wqsum[i] = sum_o Wq[o][i]
__global__ __launch_bounds__(128) void wq_colsum_kernel(const float* __restrict__ Wq,
                                                        float* __restrict__ wqsum) {
  int i = threadIdx.x;
  float s = 0.f;
#pragma unroll 8
  for (int o = 0; o < C_; ++o) s += Wq[o * C_ + i];
  wqsum[i] = s;
}

// Split Wk, Wv into bf16 hi/lo pairs (RNE hi, RNE residual): x ~= hi + lo, err ~2^-17.
__global__ __launch_bounds__(256) void w_convert_kernel(
    const float* __restrict__ Wk, const float* __restrict__ Wv,
    unsigned short* __restrict__ WkHi, unsigned short* __restrict__ WkLo,
    unsigned short* __restrict__ WvHi, unsigned short* __restrict__ WvLo) {
  int idx = blockIdx.x * 256 + threadIdx.x;  // 0..16383
  {
    float x = Wk[idx];
    unsigned short h = bf16_rn(x);
    WkHi[idx] = h;
    WkLo[idx] = bf16_rn(x - __uint_as_float(((unsigned)h) << 16));
  }
  {
    float x = Wv[idx];
    unsigned short h = bf16_rn(x);
    WvHi[idx] = h;
    WvLo[idx] = bf16_rn(x - __uint_as_float(((unsigned)h) << 16));
  }
}

// Main: one block per (batch, 64-col tile). 4 waves; wave w owns cols 16w..16w+15.
// MFMA 16x16x32 bf16, split-precision (3 mfma per product).
// LDS X layout: [n][i] bf16, rows of 128, 8-elem chunks XOR-swizzled by
// f(n) = (n&15) ^ ((n>>2)&7)  (keeps ds_read_b128 frags contiguous, writes ~2-way).
__global__ __launch_bounds__(256, 2) void csa_mfma_kernel(
    const float* __restrict__ feature, const float* __restrict__ position,
    const float* __restrict__ wqsum,
    const unsigned short* __restrict__ WkHi, const unsigned short* __restrict__ WkLo,
    const unsigned short* __restrict__ WvHi, const unsigned short* __restrict__ WvLo,
    float* __restrict__ out) {
  __shared__ unsigned short posHi[TN * 128];
  __shared__ unsigned short posLo[TN * 128];
  __shared__ unsigned short featHi[TN * 128];
  __shared__ unsigned short featLo[TN * 128];

  const int tid = threadIdx.x;
  const int lane = tid & 63;
  const int w = tid >> 6;
  const int m = lane & 15;   // col within wave tile / A row within j-tile
  const int q = lane >> 4;   // quad
  const int b = blockIdx.x >> 8;
  const int n0 = (blockIdx.x & 255) * TN;

  const float* pos_g = position + (size_t)b * C_ * N_ + n0;
  const float* feat_g = feature + (size_t)b * C_ * N_ + n0;

  // ---- stage + convert both tiles to hi/lo bf16 in LDS ----
  {
    const int g = tid >> 4;          // 0..15
    const int n4 = (tid & 15) * 4;   // col group
#pragma unroll
    for (int it = 0; it < 4; ++it) {
      int i = 32 * it + 2 * g;  // even row; handle rows i, i+1
      float4 p0 = *(const float4*)(pos_g + (size_t)i * N_ + n4);
      float4 p1 = *(const float4*)(pos_g + (size_t)(i + 1) * N_ + n4);
      float4 f0 = *(const float4*)(feat_g + (size_t)i * N_ + n4);
      float4 f1 = *(const float4*)(feat_g + (size_t)(i + 1) * N_ + n4);
      const float* P0 = (const float*)&p0;
      const float* P1 = (const float*)&p1;
      const float* F0 = (const float*)&f0;
      const float* F1 = (const float*)&f1;
      int c8 = (i >> 3) * 8;
      int ioff = i & 7;  // even
#pragma unroll
      for (int d = 0; d < 4; ++d) {
        int n = n4 + d;
        int fn8 = ((n & 15) ^ ((n >> 2) & 7)) * 8;
        int hw = n * 128 + (c8 ^ fn8) + ioff;
        {
          unsigned short h0 = bf16_rn(P0[d]), h1 = bf16_rn(P1[d]);
          float l0 = P0[d] - __uint_as_float(((unsigned)h0) << 16);
          float l1 = P1[d] - __uint_as_float(((unsigned)h1) << 16);
          *(unsigned*)(posHi + hw) = (unsigned)h0 | ((unsigned)h1 << 16);
          *(unsigned*)(posLo + hw) = (unsigned)bf16_rn(l0) | ((unsigned)bf16_rn(l1) << 16);
        }
        {
          unsigned short h0 = bf16_rn(F0[d]), h1 = bf16_rn(F1[d]);
          float l0 = F0[d] - __uint_as_float(((unsigned)h0) << 16);
          float l1 = F1[d] - __uint_as_float(((unsigned)h1) << 16);
          *(unsigned*)(featHi + hw) = (unsigned)h0 | ((unsigned)h1 << 16);
          *(unsigned*)(featLo + hw) = (unsigned)bf16_rn(l0) | ((unsigned)bf16_rn(l1) << 16);
        }
      }
    }
  }
  __syncthreads();

  const int nloc = 16 * w + m;  // this lane's column (B n / D col)
  const int fn8 = ((nloc & 15) ^ ((nloc >> 2) & 7)) * 8;
  const int rowbase = nloc * 128;

  // ---- k-GEMM: k[j][nloc] for j = jt*16 + q*4 + reg ----
  f32x4 acck[8];
#pragma unroll
  for (int jt = 0; jt < 8; ++jt) acck[jt] = (f32x4){0.f, 0.f, 0.f, 0.f};

#pragma unroll
  for (int kk = 0; kk < 4; ++kk) {
    int bw = rowbase + (((kk * 4 + q) * 8) ^ fn8);
    short8 bHi = *(const short8*)(posHi + bw);
    short8 bLo = *(const short8*)(posLo + bw);
#pragma unroll
    for (int jt = 0; jt < 8; ++jt) {
      int woff = (jt * 16 + m) * 128 + kk * 32 + q * 8;
      short8 aHi = *(const short8*)(WkHi + woff);
      short8 aLo = *(const short8*)(WkLo + woff);
      acck[jt] = __builtin_amdgcn_mfma_f32_16x16x32_bf16(aHi, bHi, acck[jt], 0, 0, 0);
      acck[jt] = __builtin_amdgcn_mfma_f32_16x16x32_bf16(aHi, bLo, acck[jt], 0, 0, 0);
      acck[jt] = __builtin_amdgcn_mfma_f32_16x16x32_bf16(aLo, bHi, acck[jt], 0, 0, 0);
    }
  }

  // ---- sq = wqsum . pos[:, nloc]  (quad q covers i in [32q, 32q+32)) ----
  float sq = 0.f;
#pragma unroll
  for (int ii = 0; ii < 16; ++ii) {
    int i = q * 32 + 2 * ii;
    int hw = rowbase + (((i >> 3) * 8) ^ fn8) + (i & 7);
    unsigned hu = *(const unsigned*)(posHi + hw);
    unsigned lu = *(const unsigned*)(posLo + hw);
    float x0 = __uint_as_float(hu << 16) + __uint_as_float(lu << 16);
    float x1 = __uint_as_float(hu & 0xFFFF0000u) + __uint_as_float(lu & 0xFFFF0000u);
    float2 wq2 = *(const float2*)(wqsum + i);
    sq = fmaf(wq2.x, x0, fmaf(wq2.y, x1, sq));
  }
  sq += __shfl_xor(sq, 16, 64);
  sq += __shfl_xor(sq, 32, 64);

  // ---- softmax over j (all j for column nloc live in this wave's quads) ----
  float ksum = 0.f;
#pragma unroll
  for (int jt = 0; jt < 8; ++jt)
#pragma unroll
    for (int r = 0; r < 4; ++r) ksum += acck[jt][r];
  ksum += __shfl_xor(ksum, 16, 64);
  ksum += __shfl_xor(ksum, 32, 64);

  float gg = sq / (1e-9f + sq * ksum);

  float lmax = -__builtin_inff();
#pragma unroll
  for (int jt = 0; jt < 8; ++jt)
#pragma unroll
    for (int r = 0; r < 4; ++r) lmax = fmaxf(lmax, gg * acck[jt][r]);
  lmax = fmaxf(lmax, __shfl_xor(lmax, 16, 64));
  lmax = fmaxf(lmax, __shfl_xor(lmax, 32, 64));

  float esum = 0.f;
#pragma unroll
  for (int jt = 0; jt < 8; ++jt)
#pragma unroll
    for (int r = 0; r < 4; ++r) {
      float p = __expf(fmaf(gg, acck[jt][r], -lmax));
      acck[jt][r] = p;  // reuse as unnormalized attention
      esum += p;
    }
  esum += __shfl_xor(esum, 16, 64);
  esum += __shfl_xor(esum, 32, 64);
  float inv = 1.0f / esum;

  // ---- v-GEMM ----
  f32x4 accv[8];
#pragma unroll
  for (int jt = 0; jt < 8; ++jt) accv[jt] = (f32x4){0.f, 0.f, 0.f, 0.f};

#pragma unroll
  for (int kk = 0; kk < 4; ++kk) {
    int bw = rowbase + (((kk * 4 + q) * 8) ^ fn8);
    short8 bHi = *(const short8*)(featHi + bw);
    short8 bLo = *(const short8*)(featLo + bw);
#pragma unroll
    for (int jt = 0; jt < 8; ++jt) {
      int woff = (jt * 16 + m) * 128 + kk * 32 + q * 8;
      short8 aHi = *(const short8*)(WvHi + woff);
      short8 aLo = *(const short8*)(WvLo + woff);
      accv[jt] = __builtin_amdgcn_mfma_f32_16x16x32_bf16(aHi, bHi, accv[jt], 0, 0, 0);
      accv[jt] = __builtin_amdgcn_mfma_f32_16x16x32_bf16(aHi, bLo, accv[jt], 0, 0, 0);
      accv[jt] = __builtin_amdgcn_mfma_f32_16x16x32_bf16(aLo, bHi, accv[jt], 0, 0, 0);
    }
  }

  // ---- epilogue: out = att*v + feat (feat reconstructed from hi+lo, err ~2^-17) ----
  float* outb = out + (size_t)b * C_ * N_ + n0 + nloc;
#pragma unroll
  for (int jt = 0; jt < 8; ++jt) {
#pragma unroll
    for (int rp = 0; rp < 2; ++rp) {
      int j = jt * 16 + q * 4 + rp * 2;  // even
      int hw = rowbase + (((j >> 3) * 8) ^ fn8) + (j & 7);
      unsigned hu = *(const unsigned*)(featHi + hw);
      unsigned lu = *(const unsigned*)(featLo + hw);
      float fv0 = __uint_as_float(hu << 16) + __uint_as_float(lu << 16);
      float fv1 = __uint_as_float(hu & 0xFFFF0000u) + __uint_as_float(lu & 0xFFFF0000u);
      float att0 = acck[jt][rp * 2] * inv;
      float att1 = acck[jt][rp * 2 + 1] * inv;
      outb[(size_t)j * N_] = fmaf(att0, accv[jt][rp * 2], fv0);
      outb[(size_t)(j + 1) * N_] = fmaf(att1, accv[jt][rp * 2 + 1], fv1);
    }
  }
}

extern "C" void kernel_launch(void* const* d_in, const int* in_sizes, int n_in,
                              void* d_out, int out_size, void* d_ws, size_t ws_size,
                              hipStream_t stream) {
  const float* feature = (const float*)d_in[0];
  const float* position = (const float*)d_in[1];
  const float* Wq = (const float*)d_in[2];
  const float* Wk = (const float*)d_in[3];
  const float* Wv = (const float*)d_in[4];
  float* out = (float*)d_out;

  char* ws = (char*)d_ws;
  float* wqsum = (float*)ws;                              // 512 B
  unsigned short* WkHi = (unsigned short*)(ws + 512);     // 32 KB each
  unsigned short* WkLo = (unsigned short*)(ws + 512 + 32768);
  unsigned short* WvHi = (unsigned short*)(ws + 512 + 65536);
  unsigned short* WvLo = (unsigned short*)(ws + 512 + 98304);

  wq_colsum_kernel<<<1, 128, 0, stream>>>(Wq, wqsum);
  w_convert_kernel<<<64, 256, 0, stream>>>(Wk, Wv, WkHi, WkLo, WvHi, WvLo);
  csa_mfma_kernel<<<B_ * (N_ / TN), 256, 0, stream>>>(feature, position, wqsum,
                                                      WkHi, WkLo, WvHi, WvLo, out);
}